// Round 5
// baseline (1461.996 us; speedup 1.0000x reference)
//
#include <hip/hip_runtime.h>
#include <hip/hip_bf16.h>
#include <stdint.h>

// ---------- types ----------
typedef __attribute__((ext_vector_type(8))) __bf16 bf16x8;
typedef __attribute__((ext_vector_type(4))) float f32x4;
typedef __attribute__((ext_vector_type(8))) unsigned short ushort8;

typedef const void __attribute__((address_space(1))) gv_t;
typedef void __attribute__((address_space(3))) lv_t;

#define GL16(g, l) __builtin_amdgcn_global_load_lds((gv_t*)(g), (lv_t*)(l), 16, 0, 0)

__device__ __forceinline__ unsigned short f2bf(float f) {
    unsigned int u = __float_as_uint(f);
    u += 0x7fffu + ((u >> 16) & 1u);
    return (unsigned short)(u >> 16);
}

// ---------- kernel 1: per-group int4 quant-dequant of W -> bf16 bits ----------
__global__ void __launch_bounds__(256) qdq_weight(const float* __restrict__ w,
                                                  unsigned short* __restrict__ wb,
                                                  int n_groups) {
    int g = blockIdx.x * 256 + threadIdx.x;
    if (g >= n_groups) return;
    const float4* p = (const float4*)w + (size_t)g * 2;
    float4 v0 = p[0], v1 = p[1];
    float t[8] = {v0.x, v0.y, v0.z, v0.w, v1.x, v1.y, v1.z, v1.w};
    float amax = 0.0f;
#pragma unroll
    for (int j = 0; j < 8; ++j) amax = fmaxf(amax, fabsf(t[j]));
    float scale = fmaxf(amax / 7.0f, 1e-8f);
    ushort8 o;
#pragma unroll
    for (int j = 0; j < 8; ++j) {
        float q = rintf(t[j] / scale);
        q = fminf(fmaxf(q, -7.0f), 7.0f);
        o[j] = f2bf(q * scale);
    }
    *((ushort8*)wb + g) = o;
}

// ---------- kernel 2: f32 -> bf16 cast of x ----------
__global__ void __launch_bounds__(256) cvt_bf16(const float* __restrict__ x,
                                                unsigned short* __restrict__ xb,
                                                int n8) {
    int i = blockIdx.x * 256 + threadIdx.x;
    if (i >= n8) return;
    const float4* p = (const float4*)x + (size_t)i * 2;
    float4 v0 = p[0], v1 = p[1];
    ushort8 o;
    o[0] = f2bf(v0.x); o[1] = f2bf(v0.y); o[2] = f2bf(v0.z); o[3] = f2bf(v0.w);
    o[4] = f2bf(v1.x); o[5] = f2bf(v1.y); o[6] = f2bf(v1.z); o[7] = f2bf(v1.w);
    *((ushort8*)xb + i) = o;
}

// ---------- kernel 3: templated ablation of the 8-phase 256x256 GEMM ----------
// RD: do per-phase ds_reads   ST: do staging + VM gates   SY: barriers
// REP: repeat the whole K-loop (timing amplification for ablation variants)
// REAL: write full C with bias (the correctness-carrying instantiation)
#define BM 256
#define BN 256
#define BK 64

#define MFMA_Q(qm, qn, AF, BF)                                                 \
    __builtin_amdgcn_s_setprio(1);                                             \
    _Pragma("unroll")                                                          \
    for (int mi = 0; mi < 4; ++mi)                                             \
        _Pragma("unroll")                                                      \
        for (int ni = 0; ni < 2; ++ni)                                         \
            _Pragma("unroll")                                                  \
            for (int ks = 0; ks < 2; ++ks)                                     \
                acc[(qm) * 4 + mi][(qn) * 2 + ni] =                            \
                    __builtin_amdgcn_mfma_f32_16x16x32_bf16(                   \
                        AF[mi][ks], BF[ni][ks],                                \
                        acc[(qm) * 4 + mi][(qn) * 2 + ni], 0, 0, 0);           \
    __builtin_amdgcn_s_setprio(0);

#define STAGE_A(b, h, kk)                                                      \
    {                                                                          \
        GL16(gA + (size_t)((h) * 64 + srow) * K + (kk) + schunk,               \
             &sA[b][h][0] + sldso);                                            \
        GL16(gA + (size_t)((h) * 64 + 128 + srow) * K + (kk) + schunk,         \
             &sA[b][h][64 * BK] + sldso);                                      \
    }
#define STAGE_B(b, h, kk)                                                      \
    {                                                                          \
        GL16(gB + (size_t)((h) * 32 + brow) * K + (kk) + schunk,               \
             &sB[b][h][0] + sldso);                                            \
        GL16(gB + (size_t)((h) * 32 + 128 + brow) * K + (kk) + schunk,         \
             &sB[b][h][64 * BK] + sldso);                                      \
    }

#define READ_A(dst, b, h)                                                      \
    _Pragma("unroll")                                                          \
    for (int mi = 0; mi < 4; ++mi) {                                           \
        const int s_ = (wr * 64 + mi * 16 + lr) * BK;                          \
        dst[mi][0] = *(const bf16x8*)&sA[b][h][s_ + e0];                       \
        dst[mi][1] = *(const bf16x8*)&sA[b][h][s_ + e1];                       \
    }
#define READ_B(dst, b, h)                                                      \
    _Pragma("unroll")                                                          \
    for (int ni = 0; ni < 2; ++ni) {                                           \
        const int s_ = (bcol + ni * 16 + lr) * BK;                             \
        dst[ni][0] = *(const bf16x8*)&sB[b][h][s_ + e0];                       \
        dst[ni][1] = *(const bf16x8*)&sB[b][h][s_ + e1];                       \
    }

#define BAR_()  asm volatile("s_barrier" ::: "memory")
#define VM_(n)  asm volatile("s_waitcnt vmcnt(" #n ")" ::: "memory")

template <int RD, int ST, int SY, int REP, int REAL>
__global__ void __launch_bounds__(512, 2)
gemmV(const unsigned short* __restrict__ A,
      const unsigned short* __restrict__ B,
      const float* __restrict__ bias,
      float* __restrict__ C,
      int M, int N, int K) {
    __shared__ unsigned short sA[2][2][128 * BK];
    __shared__ unsigned short sB[2][2][128 * BK];

    const int t  = threadIdx.x;
    const int w  = t >> 6;
    const int ln = t & 63;
    const int lr = ln & 15;
    const int lk = ln >> 4;
    const int wr = w >> 2;
    const int wc = w & 3;
    const int bcol = (wc >> 1) * 64 + (wc & 1) * 32;

    const int nbn = N / BN;
    const int bid = blockIdx.x;
    const int swz = ((int)gridDim.x & 7) ? bid
                  : ((bid & 7) * ((int)gridDim.x >> 3) + (bid >> 3));
    const int m0 = (swz / nbn) * BM;
    const int n0 = (swz % nbn) * BN;

    const unsigned short* gA = A + (size_t)m0 * K;
    const unsigned short* gB = B + (size_t)n0 * K;

    const int srow   = t >> 3;
    const int brow   = (srow & 31) + ((srow >> 5) << 6);
    const int schunk = (((t & 7) ^ (srow & 7)) << 3);
    const int sldso  = (w * 8) * BK;

    const int sw = (lr & 7) << 3;
    const int e0 = (lk * 8) ^ sw;
    const int e1 = (32 + lk * 8) ^ sw;

    f32x4 acc[8][4];
#pragma unroll
    for (int i = 0; i < 8; ++i)
#pragma unroll
        for (int j = 0; j < 4; ++j)
            acc[i][j] = (f32x4)(0.0f);

    const int NT = K / BK;
    const int J  = NT / 2;

    bf16x8 a0f[4][2], a1f[4][2], b0f[2][2], b1f[2][2];

    // prologue (always executed once): fills tile0/buf0 + tile1 h0 halves
    STAGE_A(0, 0, 0);
    STAGE_B(0, 0, 0);
    STAGE_B(0, 1, 0);
    STAGE_A(0, 1, 0);
    STAGE_A(1, 0, BK);
    STAGE_B(1, 0, BK);
    STAGE_B(1, 1, BK);
    VM_(8);
    BAR_();
    READ_A(a0f, 0, 0);
    if constexpr (!RD) {       // variants without per-phase reads need all frags live
        READ_A(a1f, 0, 1);
        READ_B(b0f, 0, 0);
        READ_B(b1f, 0, 1);
    }

    for (int rep = 0; rep < REP; ++rep) {
        for (int it = 0; it < J; ++it) {
            const int t0 = 2 * it;
            const int k1 = (t0 + 1) * BK;
            int k2 = (t0 + 2) * BK;  if (k2 >= K) k2 = 0;
            int k3 = (t0 + 3) * BK;  if (k3 >= K) k3 = 0;

            // ph1
            if constexpr (RD) { READ_B(b0f, 0, 0); READ_B(b1f, 0, 1); }
            if constexpr (ST) STAGE_A(1, 1, k1);
            MFMA_Q(0, 0, a0f, b0f);
            if constexpr (ST) VM_(8);
            if constexpr (SY) BAR_();

            // ph2
            if constexpr (RD) READ_A(a1f, 0, 1);
            if constexpr (ST) STAGE_A(0, 0, k2);
            MFMA_Q(0, 1, a0f, b1f);
            if constexpr (ST) VM_(8);
            if constexpr (SY) BAR_();

            // ph3
            if constexpr (RD) READ_A(a0f, 1, 0);
            if constexpr (ST) STAGE_B(0, 0, k2);
            MFMA_Q(1, 1, a1f, b1f);
            if constexpr (ST) VM_(8);
            if constexpr (SY) BAR_();

            // ph4
            if constexpr (ST) STAGE_B(0, 1, k2);
            MFMA_Q(1, 0, a1f, b0f);
            if constexpr (ST) VM_(8);
            if constexpr (SY) BAR_();

            // ph5
            if constexpr (RD) { READ_B(b0f, 1, 0); READ_B(b1f, 1, 1); }
            if constexpr (ST) STAGE_A(0, 1, k2);
            MFMA_Q(0, 0, a0f, b0f);
            if constexpr (ST) VM_(8);
            if constexpr (SY) BAR_();

            // ph6
            if constexpr (RD) READ_A(a1f, 1, 1);
            if constexpr (ST) STAGE_A(1, 0, k3);
            MFMA_Q(0, 1, a0f, b1f);
            if constexpr (ST) VM_(8);
            if constexpr (SY) BAR_();

            // ph7
            if constexpr (RD) READ_A(a0f, 0, 0);
            if constexpr (ST) STAGE_B(1, 0, k3);
            MFMA_Q(1, 1, a1f, b1f);
            if constexpr (ST) VM_(8);
            if constexpr (SY) BAR_();

            // ph8
            if constexpr (ST) STAGE_B(1, 1, k3);
            MFMA_Q(1, 0, a1f, b0f);
            if constexpr (ST) VM_(8);
            if constexpr (SY) BAR_();
        }
    }

    if constexpr (REAL) {
#pragma unroll
        for (int j = 0; j < 4; ++j) {
            const int n = n0 + wc * 64 + (j >> 1) * 32 + (j & 1) * 16 + lr;
            const float bv = bias[n];
#pragma unroll
            for (int i = 0; i < 8; ++i) {
                const int m = m0 + wr * 128 + (i >> 2) * 64 + (i & 3) * 16 + lk * 4;
                f32x4 v = acc[i][j];
                C[(size_t)(m + 0) * N + n] = v[0] + bv;
                C[(size_t)(m + 1) * N + n] = v[1] + bv;
                C[(size_t)(m + 2) * N + n] = v[2] + bv;
                C[(size_t)(m + 3) * N + n] = v[3] + bv;
            }
        }
    } else {
        // keep all MFMA live without burning write BW: only one block stores
        if (m0 == 0 && n0 == 0) {
#pragma unroll
            for (int j = 0; j < 4; ++j) {
                const int n = wc * 64 + (j >> 1) * 32 + (j & 1) * 16 + lr;
#pragma unroll
                for (int i = 0; i < 8; ++i) {
                    const int m = wr * 128 + (i >> 2) * 64 + (i & 3) * 16 + lk * 4;
                    f32x4 v = acc[i][j];
                    C[(size_t)(m + 0) * N + n] = v[0];
                    C[(size_t)(m + 1) * N + n] = v[1];
                    C[(size_t)(m + 2) * N + n] = v[2];
                    C[(size_t)(m + 3) * N + n] = v[3];
                }
            }
        }
    }
}

// ---------- launcher ----------
extern "C" void kernel_launch(void* const* d_in, const int* in_sizes, int n_in,
                              void* d_out, int out_size, void* d_ws, size_t ws_size,
                              hipStream_t stream) {
    const float* x    = (const float*)d_in[0];
    const float* wgt  = (const float*)d_in[1];
    const float* bias = (const float*)d_in[2];
    float* out        = (float*)d_out;

    const int dout = in_sizes[2];
    const int din  = in_sizes[1] / dout;
    const int M    = in_sizes[0] / din;
    const int N    = dout, K = din;

    unsigned short* xb = (unsigned short*)d_ws;
    unsigned short* wb = xb + (size_t)M * K;

    const int ng_w = (N * K) / 8;
    qdq_weight<<<(ng_w + 255) / 256, 256, 0, stream>>>(wgt, wb, ng_w);

    const int n8_x = (M * K) / 8;
    cvt_bf16<<<(n8_x + 255) / 256, 256, 0, stream>>>(x, xb, n8_x);

    const int nwg = (M / BM) * (N / BN);     // 512

    // --- ablation variants (outputs overwritten by the REAL run below) ---
    // V1: no per-phase ds_reads (stage+VM+bar kept), x2 reps
    gemmV<0, 1, 1, 2, 0><<<nwg, 512, 0, stream>>>(xb, wb, bias, out, M, N, K);
    // V2: no staging / no VM (reads+bar kept), x2 reps
    gemmV<1, 0, 1, 2, 0><<<nwg, 512, 0, stream>>>(xb, wb, bias, out, M, N, K);
    // V4: MFMA + barriers only, x4 reps
    gemmV<0, 0, 1, 4, 0><<<nwg, 512, 0, stream>>>(xb, wb, bias, out, M, N, K);

    // --- the real kernel (correctness-carrying), runs last ---
    gemmV<1, 1, 1, 1, 1><<<nwg, 512, 0, stream>>>(xb, wb, bias, out, M, N, K);
}

// Round 6
// 296.794 us; speedup vs baseline: 4.9260x; 4.9260x over previous
//
#include <hip/hip_runtime.h>
#include <hip/hip_bf16.h>
#include <stdint.h>

// ---------- types ----------
typedef __attribute__((ext_vector_type(8))) __bf16 bf16x8;
typedef __attribute__((ext_vector_type(4))) float f32x4;
typedef __attribute__((ext_vector_type(8))) unsigned short ushort8;

typedef const void __attribute__((address_space(1))) gv_t;
typedef void __attribute__((address_space(3))) lv_t;

#define GL16(g, l) __builtin_amdgcn_global_load_lds((gv_t*)(g), (lv_t*)(l), 16, 0, 0)

__device__ __forceinline__ unsigned short f2bf(float f) {
    unsigned int u = __float_as_uint(f);
    u += 0x7fffu + ((u >> 16) & 1u);
    return (unsigned short)(u >> 16);
}

// ---------- kernel 1: per-group int4 quant-dequant of W -> bf16 bits ----------
__global__ void __launch_bounds__(256) qdq_weight(const float* __restrict__ w,
                                                  unsigned short* __restrict__ wb,
                                                  int n_groups) {
    int g = blockIdx.x * 256 + threadIdx.x;
    if (g >= n_groups) return;
    const float4* p = (const float4*)w + (size_t)g * 2;
    float4 v0 = p[0], v1 = p[1];
    float t[8] = {v0.x, v0.y, v0.z, v0.w, v1.x, v1.y, v1.z, v1.w};
    float amax = 0.0f;
#pragma unroll
    for (int j = 0; j < 8; ++j) amax = fmaxf(amax, fabsf(t[j]));
    float scale = fmaxf(amax / 7.0f, 1e-8f);
    ushort8 o;
#pragma unroll
    for (int j = 0; j < 8; ++j) {
        float q = rintf(t[j] / scale);
        q = fminf(fmaxf(q, -7.0f), 7.0f);
        o[j] = f2bf(q * scale);
    }
    *((ushort8*)wb + g) = o;
}

// ---------- kernel 2: f32 -> bf16 cast of x ----------
__global__ void __launch_bounds__(256) cvt_bf16(const float* __restrict__ x,
                                                unsigned short* __restrict__ xb,
                                                int n8) {
    int i = blockIdx.x * 256 + threadIdx.x;
    if (i >= n8) return;
    const float4* p = (const float4*)x + (size_t)i * 2;
    float4 v0 = p[0], v1 = p[1];
    ushort8 o;
    o[0] = f2bf(v0.x); o[1] = f2bf(v0.y); o[2] = f2bf(v0.z); o[3] = f2bf(v0.w);
    o[4] = f2bf(v1.x); o[5] = f2bf(v1.y); o[6] = f2bf(v1.z); o[7] = f2bf(v1.w);
    *((ushort8*)xb + i) = o;
}

// ---------- kernel 3: 256x256 8-wave m201-faithful 8-phase bf16 GEMM ----------
// Phase = { ds_reads (same-phase) | 1 half-tile stage | [lgkm hint] ;
//           s_barrier ; lgkmcnt(0) ; sched_barrier(0) ;
//           setprio(1) 16xMFMA setprio(0) ; s_barrier }
// vmcnt(4) only at phases 4 and 8.
#define BM 256
#define BN 256
#define BK 64

#define MFMA_Q(qm, qn, AF, BF)                                                 \
    __builtin_amdgcn_s_setprio(1);                                             \
    _Pragma("unroll")                                                          \
    for (int mi = 0; mi < 4; ++mi)                                             \
        _Pragma("unroll")                                                      \
        for (int ni = 0; ni < 2; ++ni)                                         \
            _Pragma("unroll")                                                  \
            for (int ks = 0; ks < 2; ++ks)                                     \
                acc[(qm) * 4 + mi][(qn) * 2 + ni] =                            \
                    __builtin_amdgcn_mfma_f32_16x16x32_bf16(                   \
                        AF[mi][ks], BF[ni][ks],                                \
                        acc[(qm) * 4 + mi][(qn) * 2 + ni], 0, 0, 0);           \
    __builtin_amdgcn_s_setprio(0);

#define STAGE_A(b, h, kk)                                                      \
    {                                                                          \
        GL16(gA + (size_t)((h) * 64 + srow) * K + (kk) + schunk,               \
             &sA[b][h][0] + sldso);                                            \
        GL16(gA + (size_t)((h) * 64 + 128 + srow) * K + (kk) + schunk,         \
             &sA[b][h][64 * BK] + sldso);                                      \
    }
#define STAGE_B(b, h, kk)                                                      \
    {                                                                          \
        GL16(gB + (size_t)((h) * 32 + brow) * K + (kk) + schunk,               \
             &sB[b][h][0] + sldso);                                            \
        GL16(gB + (size_t)((h) * 32 + 128 + brow) * K + (kk) + schunk,         \
             &sB[b][h][64 * BK] + sldso);                                      \
    }

#define READ_A(dst, b, h)                                                      \
    _Pragma("unroll")                                                          \
    for (int mi = 0; mi < 4; ++mi) {                                           \
        const int s_ = (wr * 64 + mi * 16 + lr) * BK;                          \
        dst[mi][0] = *(const bf16x8*)&sA[b][h][s_ + e0];                       \
        dst[mi][1] = *(const bf16x8*)&sA[b][h][s_ + e1];                       \
    }
#define READ_B(dst, b, h)                                                      \
    _Pragma("unroll")                                                          \
    for (int ni = 0; ni < 2; ++ni) {                                           \
        const int s_ = (bcol + ni * 16 + lr) * BK;                             \
        dst[ni][0] = *(const bf16x8*)&sB[b][h][s_ + e0];                       \
        dst[ni][1] = *(const bf16x8*)&sB[b][h][s_ + e1];                       \
    }

#define BAR_()     asm volatile("s_barrier" ::: "memory")
#define VM_(n)     asm volatile("s_waitcnt vmcnt(" #n ")" ::: "memory")
#define LGKM_(n)   asm volatile("s_waitcnt lgkmcnt(" #n ")" ::: "memory")
#define SCHEDBAR() __builtin_amdgcn_sched_barrier(0)

// one phase: reads+stage before open barrier; clean MFMA cluster after
#define PHASE(RDS, STG, QM, QN, AF, BF, HINT, VMQ)                             \
    {                                                                          \
        RDS;                                                                   \
        STG;                                                                   \
        HINT;                                                                  \
        BAR_();                                                                \
        LGKM_(0);                                                              \
        SCHEDBAR();                                                            \
        MFMA_Q(QM, QN, AF, BF);                                                \
        VMQ;                                                                   \
        BAR_();                                                                \
    }

__global__ void __launch_bounds__(512, 2)
gemm256(const unsigned short* __restrict__ A,   // [M][K] bf16 bits (x)
        const unsigned short* __restrict__ B,   // [N][K] bf16 bits (w_deq)
        const float* __restrict__ bias,
        float* __restrict__ C,
        int M, int N, int K) {
    __shared__ unsigned short sA[2][2][128 * BK];
    __shared__ unsigned short sB[2][2][128 * BK];

    const int t  = threadIdx.x;
    const int w  = t >> 6;
    const int ln = t & 63;
    const int lr = ln & 15;
    const int lk = ln >> 4;
    const int wr = w >> 2;
    const int wc = w & 3;
    const int bcol = (wc >> 1) * 64 + (wc & 1) * 32;

    // T1: bijective XCD swizzle (gridDim.x % 8 == 0 here)
    const int nbn = N / BN;
    const int bid = blockIdx.x;
    const int swz = ((int)gridDim.x & 7) ? bid
                  : ((bid & 7) * ((int)gridDim.x >> 3) + (bid >> 3));
    const int m0 = (swz / nbn) * BM;
    const int n0 = (swz % nbn) * BN;

    const unsigned short* gA = A + (size_t)m0 * K;
    const unsigned short* gB = B + (size_t)n0 * K;

    const int srow   = t >> 3;
    const int brow   = (srow & 31) + ((srow >> 5) << 6);
    const int schunk = (((t & 7) ^ (srow & 7)) << 3);
    const int sldso  = (w * 8) * BK;

    const int sw = (lr & 7) << 3;
    const int e0 = (lk * 8) ^ sw;
    const int e1 = (32 + lk * 8) ^ sw;

    f32x4 acc[8][4];
#pragma unroll
    for (int i = 0; i < 8; ++i)
#pragma unroll
        for (int j = 0; j < 4; ++j)
            acc[i][j] = (f32x4)(0.0f);

    const int NT = K / BK;   // even
    const int J  = NT / 2;

    bf16x8 a0f[4][2], a1f[4][2], b0f[2][2], b1f[2][2];

    // prologue: buf0 = tile0 (4 halves), then buf1.h0 = tile1 (mimics ph7,8)
    STAGE_A(0, 0, 0);
    STAGE_B(0, 0, 0);
    STAGE_A(0, 1, 0);
    STAGE_B(0, 1, 0);
    STAGE_A(1, 0, BK);
    STAGE_B(1, 0, BK);
    VM_(4);            // buf0 complete; buf1.h0 pair stays in flight
    BAR_();

    for (int it = 0; it < J; ++it) {
        const int t0 = 2 * it;
        const int k1 = (t0 + 1) * BK;
        int k2 = (t0 + 2) * BK;  if (k2 >= K) k2 = 0;   // clamped: dead data
        int k3 = (t0 + 3) * BK;  if (k3 >= K) k3 = 0;

        // ph1: read a0,b0 (buf0.h0); stage buf1.Ah1[t0+1]; Q00
        PHASE(READ_A(a0f, 0, 0); READ_B(b0f, 0, 0),
              STAGE_A(1, 1, k1), 0, 0, a0f, b0f, LGKM_(8), );
        // ph2: read a1 (buf0.h1); stage buf1.Bh1[t0+1]; Q10
        PHASE(READ_A(a1f, 0, 1),
              STAGE_B(1, 1, k1), 1, 0, a1f, b0f, , );
        // ph3: read b1 (buf0.h1); stage buf0.Ah0[t0+2]; Q11
        PHASE(READ_B(b1f, 0, 1),
              STAGE_A(0, 0, k2), 1, 1, a1f, b1f, , );
        // ph4: stage buf0.Bh0[t0+2]; Q01; vmcnt(4) -> drains ph1,ph2 (+prev ph7,8)
        PHASE(, STAGE_B(0, 0, k2), 0, 1, a0f, b1f, , VM_(4));

        // ph5: read a0,b0 (buf1.h0); stage buf0.Ah1[t0+2]; Q00
        PHASE(READ_A(a0f, 1, 0); READ_B(b0f, 1, 0),
              STAGE_A(0, 1, k2), 0, 0, a0f, b0f, LGKM_(8), );
        // ph6: read a1 (buf1.h1); stage buf0.Bh1[t0+2]; Q10
        PHASE(READ_A(a1f, 1, 1),
              STAGE_B(0, 1, k2), 1, 0, a1f, b0f, , );
        // ph7: read b1 (buf1.h1); stage buf1.Ah0[t0+3]; Q11
        PHASE(READ_B(b1f, 1, 1),
              STAGE_A(1, 0, k3), 1, 1, a1f, b1f, , );
        // ph8: stage buf1.Bh0[t0+3]; Q01; vmcnt(4) -> drains ph3..ph6 (buf0 next)
        PHASE(, STAGE_B(1, 0, k3), 0, 1, a0f, b1f, , VM_(4));
    }

    // epilogue: C/D layout col = lane&15, row = (lane>>4)*4 + reg
#pragma unroll
    for (int j = 0; j < 4; ++j) {
        const int n = n0 + wc * 64 + (j >> 1) * 32 + (j & 1) * 16 + lr;
        const float bv = bias[n];
#pragma unroll
        for (int i = 0; i < 8; ++i) {
            const int m = m0 + wr * 128 + (i >> 2) * 64 + (i & 3) * 16 + lk * 4;
            f32x4 v = acc[i][j];
            C[(size_t)(m + 0) * N + n] = v[0] + bv;
            C[(size_t)(m + 1) * N + n] = v[1] + bv;
            C[(size_t)(m + 2) * N + n] = v[2] + bv;
            C[(size_t)(m + 3) * N + n] = v[3] + bv;
        }
    }
}

// ---------- launcher ----------
extern "C" void kernel_launch(void* const* d_in, const int* in_sizes, int n_in,
                              void* d_out, int out_size, void* d_ws, size_t ws_size,
                              hipStream_t stream) {
    const float* x    = (const float*)d_in[0];
    const float* wgt  = (const float*)d_in[1];
    const float* bias = (const float*)d_in[2];
    float* out        = (float*)d_out;

    const int dout = in_sizes[2];
    const int din  = in_sizes[1] / dout;
    const int M    = in_sizes[0] / din;
    const int N    = dout, K = din;

    unsigned short* xb = (unsigned short*)d_ws;
    unsigned short* wb = xb + (size_t)M * K;

    const int ng_w = (N * K) / 8;
    qdq_weight<<<(ng_w + 255) / 256, 256, 0, stream>>>(wgt, wb, ng_w);

    const int n8_x = (M * K) / 8;
    cvt_bf16<<<(n8_x + 255) / 256, 256, 0, stream>>>(x, xb, n8_x);

    const int nwg = (M / BM) * (N / BN);     // 512, % 8 == 0
    gemm256<<<nwg, 512, 0, stream>>>(xb, wb, bias, out, M, N, K);
}